// Round 1
// 229.193 us; speedup vs baseline: 1.0412x; 1.0412x over previous
//
#include <hip/hip_runtime.h>
#include <hip/hip_bf16.h>

typedef __bf16 bf16x8 __attribute__((ext_vector_type(8)));
typedef __bf16 bf16x4 __attribute__((ext_vector_type(4)));
typedef float  f32x4  __attribute__((ext_vector_type(4)));

// Problem constants: B=32, N=4096, H=256, TDIM=128, K=2, R=2

// ---- workspace byte offsets (total ~41 MB of 256 MB) ----
static constexpr size_t WS_A     = 0;                   // 5 f32 combine coeffs
static constexpr size_t WS_TOUT  = 1024;                // t_out [32,256] f32
static constexpr size_t WS_H0    = 65536;               // h0 [32,256] f32 (atomic acc)
static constexpr size_t WS_UB    = 131072;              // u [32,256] bf16
static constexpr size_t WS_XB    = 262144;              // x bf16 [32,4096]
static constexpr size_t WS_G2B   = 524288;              // g2 bf16 [32,4096]
static constexpr size_t WS_ZB1   = 1048576;             // zb1..zb3 bf16 [32,4096] each
static constexpr size_t WS_ZBSTR = 262144;
static constexpr size_t WS_Z1    = 2097152;             // z1..z4 f32 [32,4096] each
static constexpr size_t WS_ZSTR  = 524288;
static constexpr size_t WS_WMAPT = 4194304;             // w_map^T [256,4096] bf16
static constexpr size_t WS_WO2T  = 6291456;             // w_o2^T [4096,256] bf16
static constexpr size_t WS_LB    = 8388608;             // L bf16 [4096,4096] (32 MB)

__device__ __forceinline__ f32x4 mfma16(bf16x8 a, bf16x8 b, f32x4 c) {
    return __builtin_amdgcn_mfma_f32_16x16x32_bf16(a, b, c, 0, 0, 0);
}

__device__ __forceinline__ bf16x8 cvt8(const float* p) {
    f32x4 lo = *(const f32x4*)p;
    f32x4 hi = *(const f32x4*)(p + 4);
    bf16x8 r;
    r[0] = (__bf16)lo[0]; r[1] = (__bf16)lo[1]; r[2] = (__bf16)lo[2]; r[3] = (__bf16)lo[3];
    r[4] = (__bf16)hi[0]; r[5] = (__bf16)hi[1]; r[6] = (__bf16)hi[2]; r[7] = (__bf16)hi[3];
    return r;
}

__device__ __forceinline__ float silu_f(float x) { return x / (1.0f + __expf(-x)); }

// 32x32 tile transpose f32 -> bf16 via LDS (256 threads)
__device__ __forceinline__ void transpose_tile(const float* __restrict__ src, int sstride,
                                               __bf16* __restrict__ dst, int dstride,
                                               int r0, int c0, float* sh, int tid) {
    const int r = tid >> 3, cg = (tid & 7) * 4;
    f32x4 v = *(const f32x4*)(src + (size_t)(r0 + r) * sstride + c0 + cg);
    sh[r * 33 + cg + 0] = v[0];
    sh[r * 33 + cg + 1] = v[1];
    sh[r * 33 + cg + 2] = v[2];
    sh[r * 33 + cg + 3] = v[3];
    __syncthreads();
    bf16x4 o;
    o[0] = (__bf16)sh[(cg + 0) * 33 + r];
    o[1] = (__bf16)sh[(cg + 1) * 33 + r];
    o[2] = (__bf16)sh[(cg + 2) * 33 + r];
    o[3] = (__bf16)sh[(cg + 3) * 33 + r];
    *(bf16x4*)(dst + (size_t)(c0 + r) * dstride + r0 + cg) = o;
}

// Node 1: coefficients, time-MLP, zero h0, x->bf16, weight transposes.
__global__ __launch_bounds__(256) void prep_kernel(
    const float* __restrict__ x, const float* __restrict__ t,
    const float* __restrict__ w_g1, const float* __restrict__ w_g2,
    const float* __restrict__ w_t1, const float* __restrict__ b_t1,
    const float* __restrict__ w_t2, const float* __restrict__ b_t2,
    const float* __restrict__ w_map, const float* __restrict__ w_o2,
    char* __restrict__ ws)
{
    __shared__ float sh[1056];
    const int bi = blockIdx.x, tid = threadIdx.x;
    if (bi == 0) {
        // 256 threads = H; each computes its 9 (k1,k2) products, reduce over h.
        const float g10 = w_g1[tid * 3 + 0], g11 = w_g1[tid * 3 + 1], g12 = w_g1[tid * 3 + 2];
        const float g20 = w_g2[tid * 3 + 0], g21 = w_g2[tid * 3 + 1], g22 = w_g2[tid * 3 + 2];
        float p[9] = {g10 * g20, g10 * g21, g10 * g22,
                      g11 * g20, g11 * g21, g11 * g22,
                      g12 * g20, g12 * g21, g12 * g22};
        const int wv = tid >> 6, ln = tid & 63;
#pragma unroll
        for (int j = 0; j < 9; ++j) {
            float v = p[j];
#pragma unroll
            for (int off = 32; off > 0; off >>= 1) v += __shfl_down(v, off);
            if (ln == 0) sh[wv * 9 + j] = v;
        }
        __syncthreads();
        if (tid == 0) {
            float s[9];
#pragma unroll
            for (int j = 0; j < 9; ++j) s[j] = sh[j] + sh[9 + j] + sh[18 + j] + sh[27 + j];
            float* a = (float*)(ws + WS_A);
            a[0] = s[0];
            a[1] = s[1] + s[3];
            a[2] = s[2] + s[4] + s[6];
            a[3] = s[5] + s[7];
            a[4] = s[8];
        }
    } else if (bi < 33) {
        const int b = bi - 1;
        float* t_out = (float*)(ws + WS_TOUT);
        if (tid < 64) {
            float fr = __expf(-9.210340371976184f * (float)tid * (1.0f / 64.0f));
            float ang = t[b] * fr;
            sh[tid]      = __cosf(ang);
            sh[64 + tid] = __sinf(ang);
        }
        __syncthreads();
        float acc = b_t1[tid];
        for (int j = 0; j < 128; ++j) acc += sh[j] * w_t1[j * 256 + tid];
        sh[128 + tid] = silu_f(acc);
        __syncthreads();
        float acc2 = b_t2[tid];
        for (int j = 0; j < 256; ++j) acc2 += sh[128 + j] * w_t2[j * 256 + tid];
        t_out[b * 256 + tid] = acc2;
    } else if (bi < 41) {
        // zero h0 (atomic accumulator for map_gemm)
        f32x4* p = (f32x4*)(ws + WS_H0);
        f32x4 z = {0.f, 0.f, 0.f, 0.f};
        p[(bi - 33) * 256 + tid] = z;
    } else if (bi < 105) {
        // x -> bf16 (hop1's B operand)
        const int e = ((bi - 41) * 256 + tid) * 8;
        *(bf16x8*)((__bf16*)(ws + WS_XB) + e) = cvt8(x + e);
    } else if (bi < 1129) {
        const int ti = bi - 105;
        transpose_tile(w_map, 256, (__bf16*)(ws + WS_WMAPT), 4096,
                       (ti >> 3) * 32, (ti & 7) * 32, sh, tid);
    } else {
        const int ti = bi - 1129;
        transpose_tile(w_o2, 4096, (__bf16*)(ws + WS_WO2T), 256,
                       (ti & 7) * 32, (ti >> 3) * 32, sh, tid);
    }
}

// Node 2 (hop 1): z1[b,m] = sum_n L[m,n] x[b,n]; also converts L -> bf16 (Lb).
// Grid 256 blocks x 1024 threads: m-tile 16, full K=4096 split over 16 waves.
__global__ __launch_bounds__(1024) void hop1_kernel(
    const float* __restrict__ L, const __bf16* __restrict__ xb,
    float* __restrict__ zout, __bf16* __restrict__ zb_out,
    __bf16* __restrict__ Lb)
{
    __shared__ float red[16][16][33];   // 33.8 KB
    const int bi = blockIdx.x, tid = threadIdx.x;
    const int wave = tid >> 6, lane = tid & 63;
    const int l15 = lane & 15, q = lane >> 4;
    const int m0 = bi * 16;
    const int kbase = wave * 256;

    const float*  lp  = L  + (size_t)(m0 + l15) * 4096;
    __bf16*       lbp = Lb + (size_t)(m0 + l15) * 4096;
    const __bf16* b0p = xb + (size_t)l15 * 4096;
    const __bf16* b1p = xb + (size_t)(l15 + 16) * 4096;

    f32x4 acc0 = {0,0,0,0}, acc1 = {0,0,0,0};
#pragma unroll
    for (int ks = 0; ks < 8; ++ks) {
        const int k = kbase + ks * 32 + q * 8;
        bf16x8 a  = cvt8(lp + k);
        *(bf16x8*)(lbp + k) = a;               // fused f32->bf16 L conversion
        bf16x8 b0 = *(const bf16x8*)(b0p + k);
        bf16x8 b1 = *(const bf16x8*)(b1p + k);
        acc0 = mfma16(a, b0, acc0);
        acc1 = mfma16(a, b1, acc1);
    }
    // C/D layout: col = lane&15 (b-dim), row = q*4+reg (m-dim)
#pragma unroll
    for (int r = 0; r < 4; ++r) {
        red[wave][q * 4 + r][l15]      = acc0[r];
        red[wave][q * 4 + r][l15 + 16] = acc1[r];
    }
    __syncthreads();
    if (tid < 512) {
        const int m = tid & 15, b = tid >> 4;
        float v = 0.f;
#pragma unroll
        for (int w = 0; w < 16; ++w) v += red[w][m][b];
        zout[(size_t)b * 4096 + m0 + m] = v;
        zb_out[(size_t)b * 4096 + m0 + m] = (__bf16)v;
    }
}

// Nodes 3-5 (hops 2-4): bf16 L, bf16 z in; f32 z out (+ optional bf16 z out).
__global__ __launch_bounds__(1024) void hop_bf_kernel(
    const __bf16* __restrict__ Lb, const __bf16* __restrict__ zb_in,
    float* __restrict__ zout, __bf16* __restrict__ zb_out)
{
    __shared__ float red[16][16][33];
    const int bi = blockIdx.x, tid = threadIdx.x;
    const int wave = tid >> 6, lane = tid & 63;
    const int l15 = lane & 15, q = lane >> 4;
    const int m0 = bi * 16;
    const int kbase = wave * 256;

    const __bf16* ap  = Lb + (size_t)(m0 + l15) * 4096;
    const __bf16* b0p = zb_in + (size_t)l15 * 4096;
    const __bf16* b1p = zb_in + (size_t)(l15 + 16) * 4096;

    f32x4 acc0 = {0,0,0,0}, acc1 = {0,0,0,0};
#pragma unroll
    for (int ks = 0; ks < 8; ++ks) {
        const int k = kbase + ks * 32 + q * 8;
        bf16x8 a  = *(const bf16x8*)(ap + k);
        bf16x8 b0 = *(const bf16x8*)(b0p + k);
        bf16x8 b1 = *(const bf16x8*)(b1p + k);
        acc0 = mfma16(a, b0, acc0);
        acc1 = mfma16(a, b1, acc1);
    }
#pragma unroll
    for (int r = 0; r < 4; ++r) {
        red[wave][q * 4 + r][l15]      = acc0[r];
        red[wave][q * 4 + r][l15 + 16] = acc1[r];
    }
    __syncthreads();
    if (tid < 512) {
        const int m = tid & 15, b = tid >> 4;
        float v = 0.f;
#pragma unroll
        for (int w = 0; w < 16; ++w) v += red[w][m][b];
        zout[(size_t)b * 4096 + m0 + m] = v;
        if (zb_out) zb_out[(size_t)b * 4096 + m0 + m] = (__bf16)v;
    }
}

// Node 6: g2 = a0*x + a1*z1 + a2*z2 + a3*z3 + a4*z4, emitted directly as bf16.
__global__ __launch_bounds__(256) void combine_kernel(
    const float* __restrict__ x,
    const float* __restrict__ z1, const float* __restrict__ z2,
    const float* __restrict__ z3, const float* __restrict__ z4,
    const float* __restrict__ a, __bf16* __restrict__ g2b)
{
    const int i = blockIdx.x * 256 + threadIdx.x;
    const float a0 = a[0], a1 = a[1], a2 = a[2], a3 = a[3], a4 = a[4];
    f32x4 r = a0 * ((const f32x4*)x)[i] + a1 * ((const f32x4*)z1)[i]
            + a2 * ((const f32x4*)z2)[i] + a3 * ((const f32x4*)z3)[i]
            + a4 * ((const f32x4*)z4)[i];
    bf16x4 o;
    o[0] = (__bf16)r[0]; o[1] = (__bf16)r[1]; o[2] = (__bf16)r[2]; o[3] = (__bf16)r[3];
    ((bf16x4*)g2b)[i] = o;
}

// Node 7: h0[b,h] += sum_n g2[b,n] * w_map[n,h]   (grid 128: btile x hp x 8 kc; 4 waves x 128k)
__global__ __launch_bounds__(256) void map_gemm_kernel(
    const __bf16* __restrict__ g2b, const __bf16* __restrict__ w_mapT,
    float* __restrict__ h0)
{
    __shared__ float red[4][16][32];
    const int bi = blockIdx.x, tid = threadIdx.x;
    const int wave = tid >> 6, lane = tid & 63;
    const int l15 = lane & 15, q = lane >> 4;
    const int btile = bi & 1;
    const int hp = (bi >> 1) & 7;
    const int kc = bi >> 4;                 // 0..7
    const int kbase = kc * 512 + wave * 128;

    const __bf16* ap  = g2b + (size_t)(btile * 16 + l15) * 4096;
    const __bf16* bp0 = w_mapT + (size_t)(hp * 32 + l15) * 4096;
    const __bf16* bp1 = w_mapT + (size_t)(hp * 32 + 16 + l15) * 4096;

    f32x4 acc0 = {0,0,0,0}, acc1 = {0,0,0,0};
#pragma unroll
    for (int ks = 0; ks < 4; ++ks) {
        const int k = kbase + ks * 32 + q * 8;
        bf16x8 a  = *(const bf16x8*)(ap + k);
        bf16x8 b0 = *(const bf16x8*)(bp0 + k);
        bf16x8 b1 = *(const bf16x8*)(bp1 + k);
        acc0 = mfma16(a, b0, acc0);
        acc1 = mfma16(a, b1, acc1);
    }
#pragma unroll
    for (int r = 0; r < 4; ++r) {
        red[wave][q * 4 + r][l15]      = acc0[r];
        red[wave][q * 4 + r][l15 + 16] = acc1[r];
    }
    __syncthreads();
    const int b_l = tid >> 4, hl = tid & 15;
#pragma unroll
    for (int s = 0; s < 2; ++s) {
        const int h_l = hl + s * 16;
        float v = red[0][b_l][h_l] + red[1][b_l][h_l] + red[2][b_l][h_l] + red[3][b_l][h_l];
        atomicAdd(h0 + (size_t)(btile * 16 + b_l) * 256 + hp * 32 + h_l, v);
    }
}

// Node 8: h = h0 + b_map; 2x(3-layer silu MLP + residual)/sqrt2; u = silu((h+t_out)@w_o1+b_o1)
// 1024 threads: col = tid&255, kg = tid>>8 (4-way K-split per layer, LDS reduce).
__global__ __launch_bounds__(1024) void resnet_kernel(
    const float* __restrict__ h0, const float* __restrict__ b_map,
    const float* __restrict__ res_w, const float* __restrict__ res_b,
    const float* __restrict__ t_out, const float* __restrict__ w_o1,
    const float* __restrict__ b_o1, __bf16* __restrict__ u_b)
{
    __shared__ float zs[256];
    __shared__ float part[4][256];
    const int b = blockIdx.x, tid = threadIdx.x;
    const int col = tid & 255, kg = tid >> 8;

    float hv = 0.f;
    if (kg == 0) {
        hv = h0[b * 256 + col] + b_map[col];
        zs[col] = hv;
    }
    __syncthreads();

#pragma unroll
    for (int r = 0; r < 2; ++r) {
        for (int i = 0; i < 3; ++i) {
            const float* W = res_w + ((size_t)(r * 3 + i) << 16) + (size_t)kg * 64 * 256 + col;
            const float* zp = zs + kg * 64;
            float a0 = 0, a1 = 0, a2 = 0, a3 = 0;
#pragma unroll
            for (int j = 0; j < 64; j += 4) {
                a0 += zp[j]     * W[(j)     * 256];
                a1 += zp[j + 1] * W[(j + 1) * 256];
                a2 += zp[j + 2] * W[(j + 2) * 256];
                a3 += zp[j + 3] * W[(j + 3) * 256];
            }
            part[kg][col] = (a0 + a1) + (a2 + a3);
            __syncthreads();
            if (kg == 0) {
                zs[col] = silu_f(res_b[(r * 3 + i) * 256 + col]
                                 + part[0][col] + part[1][col] + part[2][col] + part[3][col]);
            }
            __syncthreads();
        }
        if (kg == 0) {
            hv = (hv + zs[col]) * 0.70710678118654752f;
            zs[col] = hv;
        }
        __syncthreads();
    }

    // head: u = silu((hv + t_out) @ w_o1 + b_o1)
    if (kg == 0) zs[col] = hv + t_out[b * 256 + col];
    __syncthreads();
    {
        const float* W = w_o1 + (size_t)kg * 64 * 256 + col;
        const float* zp = zs + kg * 64;
        float a0 = 0, a1 = 0, a2 = 0, a3 = 0;
#pragma unroll
        for (int j = 0; j < 64; j += 4) {
            a0 += zp[j]     * W[(j)     * 256];
            a1 += zp[j + 1] * W[(j + 1) * 256];
            a2 += zp[j + 2] * W[(j + 2) * 256];
            a3 += zp[j + 3] * W[(j + 3) * 256];
        }
        part[kg][col] = (a0 + a1) + (a2 + a3);
    }
    __syncthreads();
    if (kg == 0) {
        u_b[b * 256 + col] = (__bf16)silu_f(b_o1[col]
            + part[0][col] + part[1][col] + part[2][col] + part[3][col]);
    }
}

// Node 9: out[b,n] = sum_h u[b,h] * w_o2[h,n] + b_o2[n]   (K=256, full-K per wave)
__global__ __launch_bounds__(256) void out_gemm_kernel(
    const __bf16* __restrict__ u_b, const __bf16* __restrict__ w_o2T,
    const float* __restrict__ b_o2, float* __restrict__ out)
{
    const int tid = threadIdx.x;
    const int wave = tid >> 6, lane = tid & 63;
    const int l15 = lane & 15, q = lane >> 4;
    const int g = blockIdx.x * 4 + wave;
    const int btile = g & 1;
    const int n0 = (g >> 1) * 32;

    const __bf16* ap  = u_b + (size_t)(btile * 16 + l15) * 256;
    const __bf16* bp0 = w_o2T + (size_t)(n0 + l15) * 256;
    const __bf16* bp1 = w_o2T + (size_t)(n0 + 16 + l15) * 256;

    f32x4 acc0 = {0,0,0,0}, acc1 = {0,0,0,0};
#pragma unroll
    for (int ks = 0; ks < 8; ++ks) {
        const int k = ks * 32 + q * 8;
        bf16x8 a  = *(const bf16x8*)(ap + k);
        bf16x8 b0 = *(const bf16x8*)(bp0 + k);
        bf16x8 b1 = *(const bf16x8*)(bp1 + k);
        acc0 = mfma16(a, b0, acc0);
        acc1 = mfma16(a, b1, acc1);
    }
    const int row = btile * 16 + q * 4;
    const int na = n0 + l15, nb = n0 + 16 + l15;
#pragma unroll
    for (int r = 0; r < 4; ++r) {
        out[(size_t)(row + r) * 4096 + na] = acc0[r] + b_o2[na];
        out[(size_t)(row + r) * 4096 + nb] = acc1[r] + b_o2[nb];
    }
}

extern "C" void kernel_launch(void* const* d_in, const int* in_sizes, int n_in,
                              void* d_out, int out_size, void* d_ws, size_t ws_size,
                              hipStream_t stream)
{
    (void)in_sizes; (void)n_in; (void)out_size; (void)ws_size;
    const float* x     = (const float*)d_in[0];
    const float* t     = (const float*)d_in[1];
    const float* L     = (const float*)d_in[2];
    const float* w_g1  = (const float*)d_in[3];
    const float* w_g2  = (const float*)d_in[4];
    const float* w_t1  = (const float*)d_in[5];
    const float* b_t1  = (const float*)d_in[6];
    const float* w_t2  = (const float*)d_in[7];
    const float* b_t2  = (const float*)d_in[8];
    const float* w_map = (const float*)d_in[9];
    const float* b_map = (const float*)d_in[10];
    const float* res_w = (const float*)d_in[11];
    const float* res_b = (const float*)d_in[12];
    const float* w_o1  = (const float*)d_in[13];
    const float* b_o1  = (const float*)d_in[14];
    const float* w_o2  = (const float*)d_in[15];
    const float* b_o2  = (const float*)d_in[16];
    float* out = (float*)d_out;
    char* ws = (char*)d_ws;

    float*  a_c  = (float*)(ws + WS_A);
    float*  tout = (float*)(ws + WS_TOUT);
    float*  h0   = (float*)(ws + WS_H0);
    __bf16* u_b  = (__bf16*)(ws + WS_UB);
    __bf16* xb   = (__bf16*)(ws + WS_XB);
    __bf16* g2b  = (__bf16*)(ws + WS_G2B);
    __bf16* zb1  = (__bf16*)(ws + WS_ZB1);
    __bf16* zb2  = (__bf16*)(ws + WS_ZB1 + WS_ZBSTR);
    __bf16* zb3  = (__bf16*)(ws + WS_ZB1 + 2 * WS_ZBSTR);
    float*  z1   = (float*)(ws + WS_Z1);
    float*  z2   = (float*)(ws + WS_Z1 + WS_ZSTR);
    float*  z3   = (float*)(ws + WS_Z1 + 2 * WS_ZSTR);
    float*  z4   = (float*)(ws + WS_Z1 + 3 * WS_ZSTR);
    __bf16* w_mapT = (__bf16*)(ws + WS_WMAPT);
    __bf16* w_o2T  = (__bf16*)(ws + WS_WO2T);
    __bf16* Lb     = (__bf16*)(ws + WS_LB);

    prep_kernel<<<2153, 256, 0, stream>>>(x, t, w_g1, w_g2, w_t1, b_t1, w_t2, b_t2,
                                          w_map, w_o2, ws);
    hop1_kernel<<<256, 1024, 0, stream>>>(L, xb, z1, zb1, Lb);
    hop_bf_kernel<<<256, 1024, 0, stream>>>(Lb, zb1, z2, zb2);
    hop_bf_kernel<<<256, 1024, 0, stream>>>(Lb, zb2, z3, zb3);
    hop_bf_kernel<<<256, 1024, 0, stream>>>(Lb, zb3, z4, nullptr);
    combine_kernel<<<128, 256, 0, stream>>>(x, z1, z2, z3, z4, a_c, g2b);
    map_gemm_kernel<<<128, 256, 0, stream>>>(g2b, w_mapT, h0);
    resnet_kernel<<<32, 1024, 0, stream>>>(h0, b_map, res_w, res_b, tout, w_o1, b_o1, u_b);
    out_gemm_kernel<<<64, 256, 0, stream>>>(u_b, w_o2T, b_o2, out);
}